// Round 16
// baseline (187.674 us; speedup 1.0000x reference)
//
#include <hip/hip_runtime.h>
#include <hip/hip_bf16.h>

// Problem constants (B,T,C,H) = (8,1024,768,12), D=64
#define Bb 8
#define Tt 1024
#define Cc 768
#define Hh 12
#define Dd 64
#define M_ROWS (Bb * Tt)      // 8192
#define QKV_N (3 * Cc)        // 2304

typedef __attribute__((ext_vector_type(8))) short s16x8;   // 8 x bf16
typedef __attribute__((ext_vector_type(4))) short s16x4;   // 4 x bf16
typedef __attribute__((ext_vector_type(4))) float f32x4;

#define AS1 __attribute__((address_space(1)))
#define AS3 __attribute__((address_space(3)))

static __device__ __forceinline__ short f2bf(float f) {
    union { float f; unsigned u; } v; v.f = f;
    unsigned r = (v.u + 0x7fffu + ((v.u >> 16) & 1u)) >> 16;  // RNE
    return (short)r;
}
// two f32 -> packed bf16x2 (TRUNCATION) in one v_perm_b32
static __device__ __forceinline__ unsigned pkt(float hi, float lo) {
    union { float f; unsigned u; } a, b; a.f = hi; b.f = lo;
    return __builtin_amdgcn_perm(a.u, b.u, 0x07060302u);
}

// ---------------------------------------------------------------------------
// Prep: all three fp32->bf16 casts + the RoPE cos/sin table.
// ---------------------------------------------------------------------------
static __device__ __forceinline__ void cast8(const float* __restrict__ in,
                                             short* __restrict__ out, int i) {
    const float4 a = ((const float4*)in)[i * 2];
    const float4 b = ((const float4*)in)[i * 2 + 1];
    s16x8 f;
    f[0] = f2bf(a.x); f[1] = f2bf(a.y); f[2] = f2bf(a.z); f[3] = f2bf(a.w);
    f[4] = f2bf(b.x); f[5] = f2bf(b.y); f[6] = f2bf(b.z); f[7] = f2bf(b.w);
    ((s16x8*)out)[i] = f;
}

#define S1 (M_ROWS * Cc / 8)   // 786432
#define S2 (QKV_N * Cc / 8)    // 221184
#define S3 (Cc * Cc / 8)       // 73728
#define SROPE (Tt * 32)        // 32768
#define PREP_THREADS (S1 + S2 + S3 + SROPE)  // 1114112 = 4352 * 256

__global__ __launch_bounds__(256) void prep_kernel(const float* __restrict__ x,
                                                   const float* __restrict__ wqkv,
                                                   const float* __restrict__ wproj,
                                                   short* __restrict__ xb,
                                                   short* __restrict__ wqkvb,
                                                   short* __restrict__ wprojb,
                                                   float2* __restrict__ cs) {
    int idx = blockIdx.x * blockDim.x + threadIdx.x;
    if (idx < S1) { cast8(x, xb, idx); return; }
    idx -= S1;
    if (idx < S2) { cast8(wqkv, wqkvb, idx); return; }
    idx -= S2;
    if (idx < S3) { cast8(wproj, wprojb, idx); return; }
    idx -= S3;
    {
        int t = idx >> 5, i = idx & 31;
        float inv_freq = exp2f(-0.41524101186092037f * (float)i);  // log2(1e4)/32
        float fr = (float)t * inv_freq;
        float2 v; v.x = cosf(fr); v.y = sinf(fr);
        cs[idx] = v;
    }
}

// ---------------------------------------------------------------------------
// bf16 MFMA GEMM (NT) — R9/R8 structure (68 VGPR + 96 AGPR = 164 <= 170 ->
// 3 waves/SIMD -> 768-block grid is a true single residency round).
// 128 x TN tile, BK=32, 4 waves x 32-row stripes, dbuf global_load_lds
// pipeline + source-side XOR swizzle, XCD bm-stripe swizzle.
// MODE 0: fp32 out.  MODE 1: bf16 out + fused RoPE epilogue; q scaled 0.125.
// ---------------------------------------------------------------------------
template <int MODE, int TN>
__global__ __launch_bounds__(256, 3) void gemm_nt_mfma(const short* __restrict__ A,
                                                       const short* __restrict__ B,
                                                       void* __restrict__ Cout,
                                                       const float2* __restrict__ cs,
                                                       int M, int N, int K, int nblocks) {
    __shared__ short As[2][128 * 32];
    __shared__ short Bs[2][TN * 32];
    constexpr int NT = TN / 16;

    const int wave = threadIdx.x >> 6;
    const int lane = threadIdx.x & 63;
    const int l16  = lane & 15;
    const int quad = lane >> 4;

    const int mb8  = (M >> 7) >> 3;
    const int xcd  = blockIdx.x & 7;
    const int slot = blockIdx.x >> 3;
    const int bm = (xcd * mb8 + slot / nblocks) * 128;
    const int bn = (slot % nblocks) * TN;

    f32x4 acc[2][NT] = {};

    auto stage = [&](int k0, int buf) {
#pragma unroll
        for (int j = 0; j < 2; j++) {                 // A: 512 chunks
            const int D = j * 256 + wave * 64 + lane;
            const int G = D >> 3;
            const int s = (G << 3) | ((D & 7) ^ (G & 7));
            const int m = s >> 2, c4 = (s & 3) * 8;
            __builtin_amdgcn_global_load_lds(
                (const AS1 unsigned*)(A + (size_t)(bm + m) * K + k0 + c4),
                (AS3 unsigned*)&As[buf][(j * 256 + wave * 64) * 8], 16, 0, 0);
        }
        constexpr int BCH = TN * 4;                   // B chunks
#pragma unroll
        for (int j = 0; j < (BCH + 255) / 256; j++) {
            if (BCH % 256 == 0 || j * 256 + wave * 64 < BCH) {  // wave-uniform
                const int D = j * 256 + wave * 64 + lane;
                const int G = D >> 3;
                const int s = (G << 3) | ((D & 7) ^ (G & 7));
                const int m = s >> 2, c4 = (s & 3) * 8;
                __builtin_amdgcn_global_load_lds(
                    (const AS1 unsigned*)(B + (size_t)(bn + m) * K + k0 + c4),
                    (AS3 unsigned*)&Bs[buf][(j * 256 + wave * 64) * 8], 16, 0, 0);
            }
        }
    };

    const int nIter = K >> 5;   // K/32
    stage(0, 0);
    for (int kt = 0; kt < nIter; kt++) {
        const int buf = kt & 1;
        __syncthreads();                       // drains loads for tile kt
        if (kt + 1 < nIter) stage((kt + 1) << 5, buf ^ 1);

        s16x8 af[2];
#pragma unroll
        for (int mt = 0; mt < 2; mt++) {
            const int m = wave * 32 + mt * 16 + l16;
            const int d = ((m & 1) * 4 + quad) ^ ((m >> 1) & 7);
            af[mt] = *(const s16x8*)&As[buf][(m >> 1) * 64 + d * 8];
        }
#pragma unroll
        for (int nt = 0; nt < NT; nt++) {
            const int n = nt * 16 + l16;
            const int d = ((n & 1) * 4 + quad) ^ ((n >> 1) & 7);
            s16x8 bf = *(const s16x8*)&Bs[buf][(n >> 1) * 64 + d * 8];
            acc[0][nt] = __builtin_amdgcn_mfma_f32_16x16x32_bf16(af[0], bf, acc[0][nt], 0, 0, 0);
            acc[1][nt] = __builtin_amdgcn_mfma_f32_16x16x32_bf16(af[1], bf, acc[1][nt], 0, 0, 0);
        }
    }

    if constexpr (MODE == 0) {
#pragma unroll
        for (int mt = 0; mt < 2; mt++)
#pragma unroll
            for (int r = 0; r < 4; r++) {
                const size_t row = bm + wave * 32 + mt * 16 + quad * 4 + r;
#pragma unroll
                for (int nt = 0; nt < NT; nt++)
                    ((float*)Cout)[row * N + bn + nt * 16 + l16] = acc[mt][nt][r];
            }
    } else {
        const bool is_v = (bn >= 2 * Cc);
        if (is_v) {
#pragma unroll
            for (int mt = 0; mt < 2; mt++)
#pragma unroll
                for (int r = 0; r < 4; r++) {
                    const size_t row = bm + wave * 32 + mt * 16 + quad * 4 + r;
#pragma unroll
                    for (int nt = 0; nt < NT; nt++)
                        ((short*)Cout)[row * N + bn + nt * 16 + l16] = f2bf(acc[mt][nt][r]);
                }
        } else {
            const float scale = (bn < Cc) ? 0.125f : 1.0f;  // q gets 1/sqrt(D)
#pragma unroll
            for (int mt = 0; mt < 2; mt++) {
#pragma unroll
                for (int r = 0; r < 4; r++) {
                    const int row = bm + wave * 32 + mt * 16 + quad * 4 + r;
                    const int t = row & (Tt - 1);
                    const float2 c0 = cs[t * 32 + l16];
                    const float2 c1 = cs[t * 32 + 16 + l16];
#pragma unroll
                    for (int hh = 0; hh < TN / 64; hh++) {
                        const float x0 = acc[mt][hh * 4 + 0][r];
                        const float x1 = acc[mt][hh * 4 + 1][r];
                        const float x2 = acc[mt][hh * 4 + 2][r];
                        const float x3 = acc[mt][hh * 4 + 3][r];
                        short* cp = (short*)Cout + (size_t)row * N + bn + hh * 64;
                        cp[l16]      = f2bf((x0 * c0.x + x2 * c0.y) * scale);
                        cp[16 + l16] = f2bf((x1 * c1.x + x3 * c1.y) * scale);
                        cp[32 + l16] = f2bf((-x0 * c0.y + x2 * c0.x) * scale);
                        cp[48 + l16] = f2bf((-x1 * c1.y + x3 * c1.x) * scale);
                    }
                }
            }
        }
    }
}

// ---------------------------------------------------------------------------
// Flash attention v4.1: KT=96 keys/tile (fewer, fatter barrier iterations).
// FIX vs R14: mask predicates use the wave's MINIMUM q (q0b / q0a), not
// q0+15 — a 96-key tile can contain keys > q for the lower rows even when
// kbase+95 <= q0+15 is false (R14's 0.328 absmax leak).
//  - K staged in wave-contiguous 24-row stripes (3 b128 chunks/thread).
//  - V staged in three 32-key slabs, transposed [d][key], pitch 104.
//  - P scratch = wave's own 16-row region of Vs[buf^1]; qb's PV then qa's
//    PV reuse it sequentially (same-wave program order).
//  - S^T formulation + pkt packed truncation.
// LDS = 54272 B <= 54613 (3 blocks/CU).
// ---------------------------------------------------------------------------
#define KSP2 72    // Ks pitch (64 d + 8)
#define VSP2 104   // Vs pitch (96 keys + 8)

__global__ __launch_bounds__(256) void flash_attn(const short* __restrict__ qkv,
                                                  short* __restrict__ y) {
    __shared__ short Ks[2][96 * KSP2];    // [key][d]
    __shared__ short Vs[2][64 * VSP2];    // [d][key]; buf^1 wave region = P scratch

    const int tid  = threadIdx.x;
    const int wave = tid >> 6;
    const int lane = tid & 63;
    const int l16  = lane & 15;
    const int quad = lane >> 4;

    const int pair = blockIdx.x / 96;     // 0..7
    const int bh   = blockIdx.x % 96;
    const int h = bh % Hh;
    const int b = bh / Hh;
    const int qa_blk = pair;              // light q-block
    const int qb_blk = 15 - pair;         // heavy q-block
    const int q0a = qa_blk * 64 + wave * 16;
    const int q0b = qb_blk * 64 + wave * 16;

    s16x8 qfa[2], qfb[2];
    {
        const short* qpa = qkv + (size_t)(b * Tt + q0a + l16) * QKV_N + h * Dd + quad * 8;
        const short* qpb = qkv + (size_t)(b * Tt + q0b + l16) * QKV_N + h * Dd + quad * 8;
        qfa[0] = *(const s16x8*)qpa;  qfa[1] = *(const s16x8*)(qpa + 32);
        qfb[0] = *(const s16x8*)qpb;  qfb[1] = *(const s16x8*)(qpb + 32);
    }

    f32x4 oa[4] = {}, ob[4] = {};         // O^T accumulators
    float la = 0.f, lb = 0.f;

    // staging maps
    const int vkey = tid & 31;            // V: key within slab
    const int dv0  = (tid >> 5) * 8;      // V: d base
    s16x8 pk[3], pv[3];                   // prefetch registers
    auto load_tile = [&](int kbase) {
#pragma unroll
        for (int j = 0; j < 3; j++) {
            const int chl = j * 64 + lane;
            const int rowl = chl >> 3, c16 = (chl & 7) * 8;
            pk[j] = *(const s16x8*)(qkv +
                (size_t)(b * Tt + kbase + wave * 24 + rowl) * QKV_N + Cc + h * Dd + c16);
            pv[j] = *(const s16x8*)(qkv +
                (size_t)(b * Tt + kbase + j * 32 + vkey) * QKV_N + 2 * Cc + h * Dd + dv0);
        }
    };
    auto store_tile = [&](int buf) {
#pragma unroll
        for (int j = 0; j < 3; j++) {
            const int chl = j * 64 + lane;
            const int rowl = chl >> 3, c16 = (chl & 7) * 8;
            *(s16x8*)&Ks[buf][(wave * 24 + rowl) * KSP2 + c16] = pk[j];
            const int key = j * 32 + vkey;
#pragma unroll
            for (int jj = 0; jj < 8; jj++)
                Vs[buf][(dv0 + jj) * VSP2 + key] = pv[j][jj];
        }
    };

    // process tile: qb always; qa optionally (do_a).  P scratch reused
    // sequentially: qb's P -> qb PV -> qa's P -> qa PV.
    auto process = [&](int buf, int kbase, bool do_a, bool mask_b, bool mask_a) {
        short* pw = &Vs[buf ^ 1][wave * 16 * VSP2];
        f32x4 ea[6];
        float rsb = 0.f;
#pragma unroll
        for (int g = 0; g < 6; g++) {
            s16x8 kf0 = *(const s16x8*)&Ks[buf][(g * 16 + l16) * KSP2 + quad * 8];
            s16x8 kf1 = *(const s16x8*)&Ks[buf][(g * 16 + l16) * KSP2 + 32 + quad * 8];
            f32x4 zb = {}, za = {};
            zb = __builtin_amdgcn_mfma_f32_16x16x32_bf16(kf0, qfb[0], zb, 0, 0, 0);
            zb = __builtin_amdgcn_mfma_f32_16x16x32_bf16(kf1, qfb[1], zb, 0, 0, 0);
            if (do_a) {
                za = __builtin_amdgcn_mfma_f32_16x16x32_bf16(kf0, qfa[0], za, 0, 0, 0);
                za = __builtin_amdgcn_mfma_f32_16x16x32_bf16(kf1, qfa[1], za, 0, 0, 0);
            }
            ea[g] = za;
            float p0[4];
#pragma unroll
            for (int r = 0; r < 4; r++) {
                float p = __expf(zb[r]);
                if (mask_b) p = (kbase + g * 16 + quad * 4 + r <= q0b + l16) ? p : 0.0f;
                p0[r] = p; rsb += p;
            }
            uint2 u; u.x = pkt(p0[1], p0[0]); u.y = pkt(p0[3], p0[2]);
            *(uint2*)&pw[l16 * VSP2 + g * 16 + quad * 4] = u;
        }
        lb += rsb;
#pragma unroll
        for (int c = 0; c < 3; c++) {
            s16x8 pb = *(const s16x8*)&pw[l16 * VSP2 + c * 32 + quad * 8];
#pragma unroll
            for (int nc = 0; nc < 4; nc++) {
                s16x8 vb = *(const s16x8*)&Vs[buf][(nc * 16 + l16) * VSP2 + c * 32 + quad * 8];
                ob[nc] = __builtin_amdgcn_mfma_f32_16x16x32_bf16(vb, pb, ob[nc], 0, 0, 0);
            }
        }
        if (!do_a) return;
        float rsa = 0.f;
#pragma unroll
        for (int g = 0; g < 6; g++) {
            float p0[4];
#pragma unroll
            for (int r = 0; r < 4; r++) {
                float p = __expf(ea[g][r]);
                if (mask_a) p = (kbase + g * 16 + quad * 4 + r <= q0a + l16) ? p : 0.0f;
                p0[r] = p; rsa += p;
            }
            uint2 u; u.x = pkt(p0[1], p0[0]); u.y = pkt(p0[3], p0[2]);
            *(uint2*)&pw[l16 * VSP2 + g * 16 + quad * 4] = u;
        }
        la += rsa;
#pragma unroll
        for (int c = 0; c < 3; c++) {
            s16x8 pa = *(const s16x8*)&pw[l16 * VSP2 + c * 32 + quad * 8];
#pragma unroll
            for (int nc = 0; nc < 4; nc++) {
                s16x8 vb = *(const s16x8*)&Vs[buf][(nc * 16 + l16) * VSP2 + c * 32 + quad * 8];
                oa[nc] = __builtin_amdgcn_mfma_f32_16x16x32_bf16(vb, pa, oa[nc], 0, 0, 0);
            }
        }
    };

    const int nb_t = ((qb_blk + 1) * 64 + 95) / 96;   // ceil tiles for qb
    const int na_t = ((qa_blk + 1) * 64 + 95) / 96;   // ceil tiles for qa

    load_tile(0);
    store_tile(0);
    for (int kt = 0; kt < nb_t; kt++) {
        __syncthreads();
        if (kt + 1 < nb_t) load_tile((kt + 1) * 96);
        const int buf = kt & 1;
        const int kbase = kt * 96;
        // mask needed iff the tile's max key exceeds the wave's MIN q
        const bool mb = (kbase + 95 > q0b);
        const bool da = (kt < na_t);
        const bool ma = da && (kbase + 95 > q0a);
        process(buf, kbase, da, mb, ma);
        if (kt + 1 < nb_t) store_tile(buf ^ 1);
    }

    // l reduction across the 4 quad-lanes sharing l16, then b64 stores
    float sa = la; sa += __shfl_xor(sa, 16, 64); sa += __shfl_xor(sa, 32, 64);
    float sb = lb; sb += __shfl_xor(sb, 16, 64); sb += __shfl_xor(sb, 32, 64);
    const float inva = 1.0f / sa;
    const float invb = 1.0f / sb;
    short* ypa = y + (size_t)(b * Tt + q0a + l16) * Cc + h * Dd + quad * 4;
    short* ypb = y + (size_t)(b * Tt + q0b + l16) * Cc + h * Dd + quad * 4;
#pragma unroll
    for (int nc = 0; nc < 4; nc++) {
        s16x4 va, vb2;
#pragma unroll
        for (int r = 0; r < 4; r++) {
            va[r]  = f2bf(oa[nc][r] * inva);
            vb2[r] = f2bf(ob[nc][r] * invb);
        }
        *(s16x4*)&ypa[nc * 16] = va;
        *(s16x4*)&ypb[nc * 16] = vb2;
    }
}

// ---------------------------------------------------------------------------
extern "C" void kernel_launch(void* const* d_in, const int* in_sizes, int n_in,
                              void* d_out, int out_size, void* d_ws, size_t ws_size,
                              hipStream_t stream) {
    const float* x      = (const float*)d_in[0];
    const float* w_qkv  = (const float*)d_in[1];
    const float* w_proj = (const float*)d_in[2];
    float* out = (float*)d_out;

    float2* cs    = (float2*)d_ws;                         // 1024*32 float2
    short* xb     = (short*)(cs + Tt * 32);                // 8192x768
    short* wqkvb  = xb + (size_t)M_ROWS * Cc;              // 2304x768
    short* wprojb = wqkvb + (size_t)QKV_N * Cc;            // 768x768
    short* qkvb   = wprojb + (size_t)Cc * Cc;              // 8192x2304
    short* yb     = qkvb + (size_t)M_ROWS * QKV_N;         // 8192x768

    prep_kernel<<<PREP_THREADS / 256, 256, 0, stream>>>(
        x, w_qkv, w_proj, xb, wqkvb, wprojb, cs);

    // qkv = x @ w_qkv.T with fused RoPE + q-scale (bf16 out): 768 blocks = 3/CU
    gemm_nt_mfma<1, 192><<<768, 256, 0, stream>>>(
        xb, wqkvb, qkvb, cs, M_ROWS, QKV_N, Cc, QKV_N / 192);

    flash_attn<<<96 * 8, 256, 0, stream>>>(qkvb, yb);

    // out = y @ w_proj.T (fp32 out): 512 blocks = 2/CU exact
    gemm_nt_mfma<0, 96><<<512, 256, 0, stream>>>(
        yb, wprojb, out, nullptr, M_ROWS, Cc, Cc, Cc / 96);
}